// Round 3
// baseline (3378.632 us; speedup 1.0000x reference)
//
#include <hip/hip_runtime.h>
#include <stdint.h>

// SNN forward: conv1+spike -> pool1+spike -> conv2+spike -> pool2+spike ->
// conv3+spike -> fc+spike, each with delay_shift between layers.
// Neuron: u = 0.75u + x; v = 0.96875v + u; s = (v>=100); v *= (1-s).
// Intermediate spikes as uint8 in d_ws.

#define T 128
#define AI 0.75f
#define AV 0.96875f
#define THETA 100.0f

__device__ __forceinline__ void neuron_step(float x, float& u, float& v, float& s) {
    u = AI * u + x;
    v = AV * v + u;
    s = (v >= THETA) ? 1.0f : 0.0f;
    v = v * (1.0f - s);
}

// ---------------- conv1 phase A: x[n][o][h][w][t], lanes over t -------------
// in: [16][2][40][40][128] float, w: [8][2][3][3] (x20)
__global__ __launch_bounds__(256) void conv1_x(
    const float* __restrict__ in, const float* __restrict__ cw,
    float* __restrict__ xout)
{
    __shared__ float wsm[144];
    if (threadIdx.x < 144) wsm[threadIdx.x] = cw[threadIdx.x] * 20.0f;
    __syncthreads();

    int gid = blockIdx.x * 256 + threadIdx.x;   // 3,276,800 total
    int t  = gid & 127;
    int hw = gid >> 7;
    int wx = hw % 40;
    int hy = (hw / 40) % 40;
    int n  = hw / 1600;

    float val[18];
    #pragma unroll
    for (int c = 0; c < 2; c++)
      #pragma unroll
      for (int dh = -1; dh <= 1; dh++)
        #pragma unroll
        for (int dw = -1; dw <= 1; dw++) {
            int q = c * 9 + (dh + 1) * 3 + (dw + 1);
            int hh = hy + dh, ww = wx + dw;
            bool ok = (hh >= 0) && (hh < 40) && (ww >= 0) && (ww < 40);
            val[q] = ok ? in[(((n * 2 + c) * 40 + hh) * 40 + ww) * T + t] : 0.0f;
        }

    #pragma unroll
    for (int o = 0; o < 8; o++) {
        float x = 0.f;
        #pragma unroll
        for (int q = 0; q < 18; q++) x += wsm[o * 18 + q] * val[q];
        xout[(((n * 8 + o) * 40 + hy) * 40 + wx) * T + t] = x;
    }
}

// ---------------- sum-pool 2x2 (*pw) on DELAYED spikes, fused scan ----------
template<int C, int HO, int WO>
__global__ __launch_bounds__(256) void pool_spike(
    const uint8_t* __restrict__ in, const float* __restrict__ pw_ptr,
    uint8_t* __restrict__ out)
{
    int id = blockIdx.x * 256 + threadIdx.x;          // N*C*HO*WO
    int wx = id % WO;
    int hy = (id / WO) % HO;
    int c  = (id / (WO * HO)) % C;
    int n  = id / (WO * HO * C);
    float pw = pw_ptr[0];

    const uint8_t* p00 = in + (((n * C + c) * (2 * HO) + 2 * hy) * (2 * WO) + 2 * wx) * T;
    const uint8_t* p01 = p00 + T;
    const uint8_t* p10 = p00 + 2 * WO * T;
    const uint8_t* p11 = p10 + T;
    uint8_t* op = out + (((n * C + c) * HO + hy) * WO + wx) * T;

    float u = 0.f, v = 0.f;
    int prev = 0;  // pooled sum at t-1 (delay_shift)
    for (int tb = 0; tb < T / 4; tb++) {
        uchar4 a = *(const uchar4*)(p00 + tb * 4);
        uchar4 b = *(const uchar4*)(p01 + tb * 4);
        uchar4 cc = *(const uchar4*)(p10 + tb * 4);
        uchar4 d = *(const uchar4*)(p11 + tb * 4);
        int s1i = a.x + b.x + cc.x + d.x;
        int s2i = a.y + b.y + cc.y + d.y;
        int s3i = a.z + b.z + cc.z + d.z;
        float s0, s1, s2, s3;
        neuron_step(pw * (float)prev, u, v, s0);
        neuron_step(pw * (float)s1i,  u, v, s1);
        neuron_step(pw * (float)s2i,  u, v, s2);
        neuron_step(pw * (float)s3i,  u, v, s3);
        prev = a.w + b.w + cc.w + d.w;
        *(uchar4*)(op + tb * 4) =
            make_uchar4((unsigned char)s0, (unsigned char)s1,
                        (unsigned char)s2, (unsigned char)s3);
    }
}

// ---------------- conv phase A (grouped): 16 outputs per thread -------------
// thread = (n, g, hy, wx, t); taps loaded once per c, reused by 16 outputs.
// Weight reads are wave-uniform (only t varies per lane) -> scalar loads.
template<int CIN, int COUT_PER, int G, int H, int W>
__global__ __launch_bounds__(256) void conv_x_all(
    const uint8_t* __restrict__ in, const float* __restrict__ cw, float scale,
    float* __restrict__ xout)
{
    int gid = blockIdx.x * 256 + threadIdx.x;
    int t  = gid % T;
    int wx = (gid / T) % W;
    int hy = (gid / (T * W)) % H;
    int g  = (gid / (T * W * H)) % G;
    int n  = gid / (T * W * H * G);

    int tm = (t == 0) ? 0 : (t - 1);                  // delay_shift
    float tmask = (t == 0) ? 0.0f : 1.0f;

    bool okh[3] = {hy > 0, true, hy < H - 1};
    bool okw[3] = {wx > 0, true, wx < W - 1};

    const uint8_t* base = in + ((n * CIN * H + hy) * W + wx) * T + tm;

    float acc[COUT_PER];
    #pragma unroll
    for (int oi = 0; oi < COUT_PER; oi++) acc[oi] = 0.f;

    #pragma unroll
    for (int c = 0; c < CIN; c++) {
        float tap[9];
        #pragma unroll
        for (int dh = 0; dh < 3; dh++)
            #pragma unroll
            for (int dw = 0; dw < 3; dw++) {
                bool ok = okh[dh] && okw[dw];
                tap[dh * 3 + dw] = ok ?
                    (float)base[(c * H * W + (dh - 1) * W + (dw - 1)) * T] : 0.f;
            }
        #pragma unroll
        for (int oi = 0; oi < COUT_PER; oi++) {
            const float* wp = cw + (((g * COUT_PER + oi) * CIN) + c) * 9;
            float a = acc[oi];
            #pragma unroll
            for (int q = 0; q < 9; q++) a += wp[q] * tap[q];
            acc[oi] = a;
        }
    }

    float sm = scale * tmask;
    #pragma unroll
    for (int oi = 0; oi < COUT_PER; oi++) {
        int o = g * COUT_PER + oi;
        xout[((n * (G * COUT_PER) + o) * H * W + hy * W + wx) * T + t] = acc[oi] * sm;
    }
}

// ---------------- conv phase B: neuron scan over precomputed x --------------
__global__ __launch_bounds__(256) void scan_spike(
    const float* __restrict__ x, uint8_t* __restrict__ out, int rows)
{
    int id = blockIdx.x * 256 + threadIdx.x;
    if (id >= rows) return;
    const float4* xp = (const float4*)(x + (size_t)id * T);
    uchar4* op = (uchar4*)(out + (size_t)id * T);
    float u = 0.f, v = 0.f;
    for (int tb = 0; tb < T / 4; tb++) {
        float4 xv = xp[tb];
        float s0, s1, s2, s3;
        neuron_step(xv.x, u, v, s0); neuron_step(xv.y, u, v, s1);
        neuron_step(xv.z, u, v, s2); neuron_step(xv.w, u, v, s3);
        op[tb] = make_uchar4((unsigned char)s0, (unsigned char)s1,
                             (unsigned char)s2, (unsigned char)s3);
    }
}

// ---------------- W transpose: fwT[c][o] = fw[o][c] -------------------------
__global__ __launch_bounds__(256) void transpose_w(
    const float* __restrict__ fw, float* __restrict__ fwT)
{
    __shared__ float tile[32][33];
    int bc = blockIdx.x % 100;   // c-tile (3200/32)
    int bo = blockIdx.x / 100;   // o-tile (512/32)
    int lx = threadIdx.x & 31;
    int ly = threadIdx.x >> 5;   // 0..7
    #pragma unroll
    for (int k = 0; k < 4; k++)
        tile[ly + 8 * k][lx] = fw[(bo * 32 + ly + 8 * k) * 3200 + bc * 32 + lx];
    __syncthreads();
    #pragma unroll
    for (int k = 0; k < 4; k++)
        fwT[(bc * 32 + ly + 8 * k) * 512 + bo * 32 + lx] = tile[lx][ly + 8 * k];
}

// ---------------- FC GEMM: ypart[ks][n][t][o] = sum_c W[o][c]*s5[n][c][t-1] -
// o-tile 128 x t-tile 128 per block, 8x8 per thread, c-split 8, c-chunk 56.
#define FC_CC 56
#define FC_ROW 140
#define FC_CRANGE 400

__global__ __launch_bounds__(256) void fc_gemm(
    const uint8_t* __restrict__ s5,   // [16][3200][128]
    const float* __restrict__ fwT,    // [3200][512] (transposed)
    float* __restrict__ ypart)        // [8][16][128][512]
{
    __shared__ float ldsW[FC_CC * FC_ROW];
    __shared__ float ldsS[FC_CC * FC_ROW];

    int bid = blockIdx.x;
    int ks = bid & 7;
    int n  = (bid >> 3) & 15;
    int ob = bid >> 7;                // 0..3
    int o0 = ob * 128;
    int cbase = ks * FC_CRANGE;
    int cend  = cbase + FC_CRANGE;

    int tid = threadIdx.x;
    int og = tid & 15;                // o_local = og*8 + i
    int tg = tid >> 4;                // t = tg*8 + j
    int wo = og * 8 + ((og >> 2) << 2);   // swizzled group offset
    int so = tg * 8 + ((tg >> 2) << 2);

    float acc[8][8];
    #pragma unroll
    for (int i = 0; i < 8; i++)
        #pragma unroll
        for (int j = 0; j < 8; j++) acc[i][j] = 0.f;

    int oL = tid & 127;               // W staging: lane over o (coalesced, no LDS conflict)
    int cH = tid >> 7;                // 0..1
    int tS = tid & 127;               // S staging: lane over t (coalesced)
    int cS = tid >> 7;                // 0..1

    for (int ch = 0; ch < 8; ch++) {
        int c0 = cbase + ch * FC_CC;
        #pragma unroll
        for (int r = 0; r < 28; r++) {
            int cc = cH * 28 + r;
            int c = c0 + cc;
            float wv = (c < cend) ? fwT[c * 512 + o0 + oL] : 0.f;
            ldsW[cc * FC_ROW + oL + ((oL >> 5) << 2)] = wv;
        }
        #pragma unroll
        for (int r = 0; r < 28; r++) {
            int cc = cS * 28 + r;
            int c = c0 + cc;
            float sv = 0.f;
            if (tS > 0 && c < cend)
                sv = (float)s5[(n * 3200 + c) * T + tS - 1];   // delay_shift
            ldsS[cc * FC_ROW + tS + ((tS >> 5) << 2)] = sv;
        }
        __syncthreads();
        #pragma unroll 4
        for (int cc = 0; cc < FC_CC; cc++) {
            const float* wr = &ldsW[cc * FC_ROW];
            const float* sr = &ldsS[cc * FC_ROW];
            float4 w0 = *(const float4*)(wr + wo);
            float4 w1 = *(const float4*)(wr + wo + 4);
            float4 sA = *(const float4*)(sr + so);
            float4 sB = *(const float4*)(sr + so + 4);
            float wv[8] = {w0.x, w0.y, w0.z, w0.w, w1.x, w1.y, w1.z, w1.w};
            float sv[8] = {sA.x, sA.y, sA.z, sA.w, sB.x, sB.y, sB.z, sB.w};
            #pragma unroll
            for (int i = 0; i < 8; i++)
                #pragma unroll
                for (int j = 0; j < 8; j++)
                    acc[i][j] += wv[i] * sv[j];
        }
        __syncthreads();
    }

    float* yp = ypart + ((ks * 16 + n) * T) * 512;
    #pragma unroll
    for (int j = 0; j < 8; j++) {
        int t = tg * 8 + j;
        float4 v0 = make_float4(acc[0][j], acc[1][j], acc[2][j], acc[3][j]);
        float4 v1 = make_float4(acc[4][j], acc[5][j], acc[6][j], acc[7][j]);
        *(float4*)&yp[t * 512 + o0 + og * 8]     = v0;
        *(float4*)&yp[t * 512 + o0 + og * 8 + 4] = v1;
    }
}

// ---------------- FC partial reduce + neuron scan + output delay ------------
__global__ __launch_bounds__(256) void fc_reduce(
    const float* __restrict__ yp, float* __restrict__ ys)
{
    int id = blockIdx.x * 256 + threadIdx.x;          // 1,048,576
    float x = 0.f;
    #pragma unroll
    for (int k = 0; k < 8; k++) x += yp[k * 1048576 + id];
    ys[id] = x;
}

__global__ __launch_bounds__(256) void fc_scan(
    const float* __restrict__ ysum,   // [16][128][512]
    float* __restrict__ out)          // [16][512][128]
{
    int id = blockIdx.x * 256 + threadIdx.x;          // 8192
    int o = id & 511;
    int n = id >> 9;
    float u = 0.f, v = 0.f;
    float prev = 0.f;                 // final delay_shift
    for (int t = 0; t < T; t++) {
        float x = ysum[(n * T + t) * 512 + o];
        float s;
        neuron_step(x, u, v, s);
        out[(n * 512 + o) * T + t] = prev;
        prev = s;
    }
}

// ---------------- launch ----------------------------------------------------
extern "C" void kernel_launch(void* const* d_in, const int* in_sizes, int n_in,
                              void* d_out, int out_size, void* d_ws, size_t ws_size,
                              hipStream_t stream) {
    const float* spike = (const float*)d_in[0];   // [16][2][40][40][128]
    const float* c1w   = (const float*)d_in[1];   // [8][2][3][3]
    const float* c2w   = (const float*)d_in[2];   // [16][8][3][3]
    const float* c3w   = (const float*)d_in[3];   // [32][16][3][3]
    const float* p1w   = (const float*)d_in[4];   // scalar
    const float* p2w   = (const float*)d_in[5];   // scalar
    const float* fcw   = (const float*)d_in[6];   // [512][3200]
    float* out = (float*)d_out;                   // [16][512][128]

    char* ws = (char*)d_ws;
    // ws layout (bytes):
    uint8_t* s1 = (uint8_t*)(ws);                 // 26,214,400
    uint8_t* s2 = (uint8_t*)(ws + 26214400);      //  6,553,600
    uint8_t* s3 = (uint8_t*)(ws + 32768000);      // 13,107,200
    uint8_t* s4 = (uint8_t*)(ws + 45875200);      //  3,276,800
    uint8_t* s5 = (uint8_t*)(ws + 49152000);      //  6,553,600
    float* xbuf  = (float*)(ws + 55705600);       // 52,428,800 (conv2/conv3 x)
    float* ypart = (float*)(ws + 55705600);       // 33,554,432 (aliases xbuf)
    float* ysumb = (float*)(ws + 55705600 + 33554432); // 4,194,304 (ends 93,454,336)
    float* xbuf1 = (float*)(ws + 93454336);       // 104,857,600 (conv1 x)
    float* fwT   = (float*)(ws + 93454336);       // 6,553,600 (reuses xbuf1 AFTER scan1)
    // total: 198,311,936 bytes

    conv1_x<<<12800, 256, 0, stream>>>(spike, c1w, xbuf1);
    scan_spike<<<800, 256, 0, stream>>>(xbuf1, s1, 204800);
    transpose_w<<<1600, 256, 0, stream>>>(fcw, fwT);   // xbuf1 dead from here
    pool_spike<8, 20, 20><<<200, 256, 0, stream>>>(s1, p1w, s2);
    conv_x_all<8, 16, 1, 20, 20><<<3200, 256, 0, stream>>>(s2, c2w, 100.0f, xbuf);
    scan_spike<<<400, 256, 0, stream>>>(xbuf, s3, 102400);
    pool_spike<16, 10, 10><<<100, 256, 0, stream>>>(s3, p2w, s4);
    conv_x_all<16, 16, 2, 10, 10><<<1600, 256, 0, stream>>>(s4, c3w, 100.0f, xbuf);
    scan_spike<<<200, 256, 0, stream>>>(xbuf, s5, 51200);
    fc_gemm<<<512, 256, 0, stream>>>(s5, fwT, ypart);
    fc_reduce<<<4096, 256, 0, stream>>>(ypart, ysumb);
    fc_scan<<<32, 256, 0, stream>>>(ysumb, out);
}

// Round 4
// 641.187 us; speedup vs baseline: 5.2693x; 5.2693x over previous
//
#include <hip/hip_runtime.h>
#include <stdint.h>

// SNN forward: conv1+spike -> pool1+spike -> conv2+spike -> pool2+spike ->
// conv3+spike -> fc+spike, each with delay_shift between layers.
// Neuron: u = 0.75u + x; v = 0.96875v + u; s = (v>=100); v *= (1-s).
// Intermediate spikes as uint8 in d_ws.

#define T 128
#define AI 0.75f
#define AV 0.96875f
#define THETA 100.0f

__device__ __forceinline__ void neuron_step(float x, float& u, float& v, float& s) {
    u = AI * u + x;
    v = AV * v + u;
    s = (v >= THETA) ? 1.0f : 0.0f;
    v = v * (1.0f - s);
}

// ---------------- conv1 phase A: x[n][o][h][w][t], lanes over t -------------
// in: [16][2][40][40][128] float, w: [8][2][3][3] (x20 folded at write).
// n from blockIdx only; weights read via uniform (SGPR) addresses.
// #pragma unroll 1 on o-loop caps scalar-load live ranges (anti-spill).
__global__ __launch_bounds__(256) void conv1_x(
    const float* __restrict__ in, const float* __restrict__ cw,
    float* __restrict__ xout)
{
    int bid = blockIdx.x;                       // 12800
    int tIdx = (bid % 800) * 256 + threadIdx.x; // within [40][40][128]
    int n = bid / 800;
    int t  = tIdx % T;
    int wx = (tIdx / T) % 40;
    int hy = tIdx / (T * 40);

    float val[18];
    #pragma unroll
    for (int c = 0; c < 2; c++)
      #pragma unroll
      for (int dh = -1; dh <= 1; dh++)
        #pragma unroll
        for (int dw = -1; dw <= 1; dw++) {
            int q = c * 9 + (dh + 1) * 3 + (dw + 1);
            int hh = hy + dh, ww = wx + dw;
            bool ok = (hh >= 0) && (hh < 40) && (ww >= 0) && (ww < 40);
            val[q] = ok ? in[(((n * 2 + c) * 40 + hh) * 40 + ww) * T + t] : 0.0f;
        }

    #pragma unroll 1
    for (int o = 0; o < 8; o++) {
        const float* wp = cw + o * 18;          // uniform -> s_load
        float a = 0.f;
        #pragma unroll
        for (int q = 0; q < 18; q++) a += wp[q] * val[q];
        xout[(((n * 8 + o) * 40 + hy) * 40 + wx) * T + t] = a * 20.0f;
    }
}

// ---------------- sum-pool 2x2 (*pw) on DELAYED spikes, fused scan ----------
template<int C, int HO, int WO>
__global__ __launch_bounds__(256) void pool_spike(
    const uint8_t* __restrict__ in, const float* __restrict__ pw_ptr,
    uint8_t* __restrict__ out)
{
    int id = blockIdx.x * 256 + threadIdx.x;          // N*C*HO*WO
    int wx = id % WO;
    int hy = (id / WO) % HO;
    int c  = (id / (WO * HO)) % C;
    int n  = id / (WO * HO * C);
    float pw = pw_ptr[0];

    const uint8_t* p00 = in + (((n * C + c) * (2 * HO) + 2 * hy) * (2 * WO) + 2 * wx) * T;
    const uint8_t* p01 = p00 + T;
    const uint8_t* p10 = p00 + 2 * WO * T;
    const uint8_t* p11 = p10 + T;
    uint8_t* op = out + (((n * C + c) * HO + hy) * WO + wx) * T;

    float u = 0.f, v = 0.f;
    int prev = 0;  // pooled sum at t-1 (delay_shift)
    for (int tb = 0; tb < T / 4; tb++) {
        uchar4 a = *(const uchar4*)(p00 + tb * 4);
        uchar4 b = *(const uchar4*)(p01 + tb * 4);
        uchar4 cc = *(const uchar4*)(p10 + tb * 4);
        uchar4 d = *(const uchar4*)(p11 + tb * 4);
        int s1i = a.x + b.x + cc.x + d.x;
        int s2i = a.y + b.y + cc.y + d.y;
        int s3i = a.z + b.z + cc.z + d.z;
        float s0, s1, s2, s3;
        neuron_step(pw * (float)prev, u, v, s0);
        neuron_step(pw * (float)s1i,  u, v, s1);
        neuron_step(pw * (float)s2i,  u, v, s2);
        neuron_step(pw * (float)s3i,  u, v, s3);
        prev = a.w + b.w + cc.w + d.w;
        *(uchar4*)(op + tb * 4) =
            make_uchar4((unsigned char)s0, (unsigned char)s1,
                        (unsigned char)s2, (unsigned char)s3);
    }
}

// ---------------- conv phase A (grouped): COUT_PER outputs per thread -------
// g,n from blockIdx ONLY (block-uniform -> weights via s_load, SGPR-resident).
// c-loop unroll 1 + sched_barrier every 4 outputs: bounded live ranges.
template<int CIN, int COUT_PER, int G, int H, int W>
__global__ __launch_bounds__(256) void conv_x_all(
    const uint8_t* __restrict__ in, const float* __restrict__ cw, float scale,
    float* __restrict__ xout)
{
    constexpr int BPG = H * W * T / 256;        // blocks per (n,g)
    int bid = blockIdx.x;
    int tIdx = (bid % BPG) * 256 + threadIdx.x;
    int gn = bid / BPG;
    int g = gn % G;                             // uniform
    int n = gn / G;                             // uniform
    int t  = tIdx % T;
    int wx = (tIdx / T) % W;
    int hy = tIdx / (T * W);

    int tm = (t == 0) ? 0 : (t - 1);            // delay_shift
    float tmask = (t == 0) ? 0.0f : 1.0f;

    bool okh[3] = {hy > 0, true, hy < H - 1};
    bool okw[3] = {wx > 0, true, wx < W - 1};

    const uint8_t* base = in + ((n * CIN * H + hy) * W + wx) * T + tm;
    const float* wbase = cw + g * COUT_PER * CIN * 9;   // uniform

    float acc[COUT_PER];
    #pragma unroll
    for (int oi = 0; oi < COUT_PER; oi++) acc[oi] = 0.f;

    #pragma unroll 1
    for (int c = 0; c < CIN; c++) {
        float tap[9];
        #pragma unroll
        for (int dh = 0; dh < 3; dh++)
            #pragma unroll
            for (int dw = 0; dw < 3; dw++) {
                bool ok = okh[dh] && okw[dw];
                tap[dh * 3 + dw] = ok ?
                    (float)base[(c * H * W + (dh - 1) * W + (dw - 1)) * T] : 0.f;
            }
        #pragma unroll
        for (int oi = 0; oi < COUT_PER; oi++) {
            if ((oi & 3) == 0) __builtin_amdgcn_sched_barrier(0);
            const float* wp = wbase + (oi * CIN + c) * 9;   // uniform
            float a = acc[oi];
            #pragma unroll
            for (int q = 0; q < 9; q++) a += wp[q] * tap[q];
            acc[oi] = a;
        }
    }

    float sm = scale * tmask;
    #pragma unroll
    for (int oi = 0; oi < COUT_PER; oi++) {
        int o = g * COUT_PER + oi;
        xout[((n * (G * COUT_PER) + o) * H * W + hy * W + wx) * T + t] = acc[oi] * sm;
    }
}

// ---------------- conv phase B: neuron scan over precomputed x --------------
__global__ __launch_bounds__(256) void scan_spike(
    const float* __restrict__ x, uint8_t* __restrict__ out, int rows)
{
    int id = blockIdx.x * 256 + threadIdx.x;
    if (id >= rows) return;
    const float4* xp = (const float4*)(x + (size_t)id * T);
    uchar4* op = (uchar4*)(out + (size_t)id * T);
    float u = 0.f, v = 0.f;
    for (int tb = 0; tb < T / 4; tb++) {
        float4 xv = xp[tb];
        float s0, s1, s2, s3;
        neuron_step(xv.x, u, v, s0); neuron_step(xv.y, u, v, s1);
        neuron_step(xv.z, u, v, s2); neuron_step(xv.w, u, v, s3);
        op[tb] = make_uchar4((unsigned char)s0, (unsigned char)s1,
                             (unsigned char)s2, (unsigned char)s3);
    }
}

// ---------------- W transpose: fwT[c][o] = fw[o][c] -------------------------
__global__ __launch_bounds__(256) void transpose_w(
    const float* __restrict__ fw, float* __restrict__ fwT)
{
    __shared__ float tile[32][33];
    int bc = blockIdx.x % 100;   // c-tile (3200/32)
    int bo = blockIdx.x / 100;   // o-tile (512/32)
    int lx = threadIdx.x & 31;
    int ly = threadIdx.x >> 5;   // 0..7
    #pragma unroll
    for (int k = 0; k < 4; k++)
        tile[ly + 8 * k][lx] = fw[(bo * 32 + ly + 8 * k) * 3200 + bc * 32 + lx];
    __syncthreads();
    #pragma unroll
    for (int k = 0; k < 4; k++)
        fwT[(bc * 32 + ly + 8 * k) * 512 + bo * 32 + lx] = tile[lx][ly + 8 * k];
}

// ---------------- FC GEMM: ypart[ks][n][t][o] = sum_c W[o][c]*s5[n][c][t-1] -
#define FC_CC 56
#define FC_ROW 140
#define FC_CRANGE 400

__global__ __launch_bounds__(256) void fc_gemm(
    const uint8_t* __restrict__ s5,   // [16][3200][128]
    const float* __restrict__ fwT,    // [3200][512] (transposed)
    float* __restrict__ ypart)        // [8][16][128][512]
{
    __shared__ float ldsW[FC_CC * FC_ROW];
    __shared__ float ldsS[FC_CC * FC_ROW];

    int bid = blockIdx.x;
    int ks = bid & 7;
    int n  = (bid >> 3) & 15;
    int ob = bid >> 7;                // 0..3
    int o0 = ob * 128;
    int cbase = ks * FC_CRANGE;
    int cend  = cbase + FC_CRANGE;

    int tid = threadIdx.x;
    int og = tid & 15;                // o_local = og*8 + i
    int tg = tid >> 4;                // t = tg*8 + j
    int wo = og * 8 + ((og >> 2) << 2);   // swizzled group offset
    int so = tg * 8 + ((tg >> 2) << 2);

    float acc[8][8];
    #pragma unroll
    for (int i = 0; i < 8; i++)
        #pragma unroll
        for (int j = 0; j < 8; j++) acc[i][j] = 0.f;

    int oL = tid & 127;               // W staging: lane over o (coalesced)
    int cH = tid >> 7;                // 0..1
    int tS = tid & 127;               // S staging: lane over t (coalesced)
    int cS = tid >> 7;                // 0..1

    for (int ch = 0; ch < 8; ch++) {
        int c0 = cbase + ch * FC_CC;
        #pragma unroll
        for (int r = 0; r < 28; r++) {
            int cc = cH * 28 + r;
            int c = c0 + cc;
            float wv = (c < cend) ? fwT[c * 512 + o0 + oL] : 0.f;
            ldsW[cc * FC_ROW + oL + ((oL >> 5) << 2)] = wv;
        }
        #pragma unroll
        for (int r = 0; r < 28; r++) {
            int cc = cS * 28 + r;
            int c = c0 + cc;
            float sv = 0.f;
            if (tS > 0 && c < cend)
                sv = (float)s5[(n * 3200 + c) * T + tS - 1];   // delay_shift
            ldsS[cc * FC_ROW + tS + ((tS >> 5) << 2)] = sv;
        }
        __syncthreads();
        #pragma unroll 4
        for (int cc = 0; cc < FC_CC; cc++) {
            const float* wr = &ldsW[cc * FC_ROW];
            const float* sr = &ldsS[cc * FC_ROW];
            float4 w0 = *(const float4*)(wr + wo);
            float4 w1 = *(const float4*)(wr + wo + 4);
            float4 sA = *(const float4*)(sr + so);
            float4 sB = *(const float4*)(sr + so + 4);
            float wv[8] = {w0.x, w0.y, w0.z, w0.w, w1.x, w1.y, w1.z, w1.w};
            float sv[8] = {sA.x, sA.y, sA.z, sA.w, sB.x, sB.y, sB.z, sB.w};
            #pragma unroll
            for (int i = 0; i < 8; i++)
                #pragma unroll
                for (int j = 0; j < 8; j++)
                    acc[i][j] += wv[i] * sv[j];
        }
        __syncthreads();
    }

    float* yp = ypart + ((ks * 16 + n) * T) * 512;
    #pragma unroll
    for (int j = 0; j < 8; j++) {
        int t = tg * 8 + j;
        float4 v0 = make_float4(acc[0][j], acc[1][j], acc[2][j], acc[3][j]);
        float4 v1 = make_float4(acc[4][j], acc[5][j], acc[6][j], acc[7][j]);
        *(float4*)&yp[t * 512 + o0 + og * 8]     = v0;
        *(float4*)&yp[t * 512 + o0 + og * 8 + 4] = v1;
    }
}

// ---------------- FC partial reduce + neuron scan + output delay ------------
__global__ __launch_bounds__(256) void fc_reduce(
    const float* __restrict__ yp, float* __restrict__ ys)
{
    int id = blockIdx.x * 256 + threadIdx.x;          // 1,048,576
    float x = 0.f;
    #pragma unroll
    for (int k = 0; k < 8; k++) x += yp[k * 1048576 + id];
    ys[id] = x;
}

__global__ __launch_bounds__(256) void fc_scan(
    const float* __restrict__ ysum,   // [16][128][512]
    float* __restrict__ out)          // [16][512][128]
{
    int id = blockIdx.x * 256 + threadIdx.x;          // 8192
    int o = id & 511;
    int n = id >> 9;
    float u = 0.f, v = 0.f;
    float prev = 0.f;                 // final delay_shift
    for (int t = 0; t < T; t++) {
        float x = ysum[(n * T + t) * 512 + o];
        float s;
        neuron_step(x, u, v, s);
        out[(n * 512 + o) * T + t] = prev;
        prev = s;
    }
}

// ---------------- launch ----------------------------------------------------
extern "C" void kernel_launch(void* const* d_in, const int* in_sizes, int n_in,
                              void* d_out, int out_size, void* d_ws, size_t ws_size,
                              hipStream_t stream) {
    const float* spike = (const float*)d_in[0];   // [16][2][40][40][128]
    const float* c1w   = (const float*)d_in[1];   // [8][2][3][3]
    const float* c2w   = (const float*)d_in[2];   // [16][8][3][3]
    const float* c3w   = (const float*)d_in[3];   // [32][16][3][3]
    const float* p1w   = (const float*)d_in[4];   // scalar
    const float* p2w   = (const float*)d_in[5];   // scalar
    const float* fcw   = (const float*)d_in[6];   // [512][3200]
    float* out = (float*)d_out;                   // [16][512][128]

    char* ws = (char*)d_ws;
    // ws layout (bytes):
    uint8_t* s1 = (uint8_t*)(ws);                 // 26,214,400
    uint8_t* s2 = (uint8_t*)(ws + 26214400);      //  6,553,600
    uint8_t* s3 = (uint8_t*)(ws + 32768000);      // 13,107,200
    uint8_t* s4 = (uint8_t*)(ws + 45875200);      //  3,276,800
    uint8_t* s5 = (uint8_t*)(ws + 49152000);      //  6,553,600
    float* xbuf  = (float*)(ws + 55705600);       // 52,428,800 (conv2/conv3 x)
    float* ypart = (float*)(ws + 55705600);       // 33,554,432 (aliases xbuf)
    float* ysumb = (float*)(ws + 55705600 + 33554432); // 4,194,304 (ends 93,454,336)
    float* xbuf1 = (float*)(ws + 93454336);       // 104,857,600 (conv1 x)
    float* fwT   = (float*)(ws + 93454336);       // 6,553,600 (reuses xbuf1 AFTER scan1)
    // total: 198,311,936 bytes

    conv1_x<<<12800, 256, 0, stream>>>(spike, c1w, xbuf1);
    scan_spike<<<800, 256, 0, stream>>>(xbuf1, s1, 204800);
    transpose_w<<<1600, 256, 0, stream>>>(fcw, fwT);   // xbuf1 dead from here
    pool_spike<8, 20, 20><<<200, 256, 0, stream>>>(s1, p1w, s2);
    conv_x_all<8, 16, 1, 20, 20><<<3200, 256, 0, stream>>>(s2, c2w, 100.0f, xbuf);
    scan_spike<<<400, 256, 0, stream>>>(xbuf, s3, 102400);
    pool_spike<16, 10, 10><<<100, 256, 0, stream>>>(s3, p2w, s4);
    conv_x_all<16, 16, 2, 10, 10><<<1600, 256, 0, stream>>>(s4, c3w, 100.0f, xbuf);
    scan_spike<<<200, 256, 0, stream>>>(xbuf, s5, 51200);
    fc_gemm<<<512, 256, 0, stream>>>(s5, fwT, ypart);
    fc_reduce<<<4096, 256, 0, stream>>>(ypart, ysumb);
    fc_scan<<<32, 256, 0, stream>>>(ysumb, out);
}

// Round 5
// 566.735 us; speedup vs baseline: 5.9616x; 1.1314x over previous
//
#include <hip/hip_runtime.h>
#include <stdint.h>

// SNN forward: conv1+spike -> pool1+spike -> conv2+spike -> pool2+spike ->
// conv3+spike -> fc+spike, each with delay_shift between layers.
// Neuron: u = 0.75u + x; v = 0.96875v + u; s = (v>=100); v *= (1-s).
// Intermediate spikes as uint8 in d_ws.

#define T 128
#define AI 0.75f
#define AV 0.96875f
#define THETA 100.0f

__device__ __forceinline__ void neuron_step(float x, float& u, float& v, float& s) {
    u = AI * u + x;
    v = AV * v + u;
    s = (v >= THETA) ? 1.0f : 0.0f;
    v = v * (1.0f - s);
}

// ---------------- conv1 phase A: x[n][o][h][w][t], lanes over t -------------
__global__ __launch_bounds__(256) void conv1_x(
    const float* __restrict__ in, const float* __restrict__ cw,
    float* __restrict__ xout)
{
    int bid = blockIdx.x;                       // 12800
    int tIdx = (bid % 800) * 256 + threadIdx.x; // within [40][40][128]
    int n = bid / 800;
    int t  = tIdx % T;
    int wx = (tIdx / T) % 40;
    int hy = tIdx / (T * 40);

    float val[18];
    #pragma unroll
    for (int c = 0; c < 2; c++)
      #pragma unroll
      for (int dh = -1; dh <= 1; dh++)
        #pragma unroll
        for (int dw = -1; dw <= 1; dw++) {
            int q = c * 9 + (dh + 1) * 3 + (dw + 1);
            int hh = hy + dh, ww = wx + dw;
            bool ok = (hh >= 0) && (hh < 40) && (ww >= 0) && (ww < 40);
            val[q] = ok ? in[(((n * 2 + c) * 40 + hh) * 40 + ww) * T + t] : 0.0f;
        }

    #pragma unroll 1
    for (int o = 0; o < 8; o++) {
        const float* wp = cw + o * 18;          // uniform -> s_load
        float a = 0.f;
        #pragma unroll
        for (int q = 0; q < 18; q++) a += wp[q] * val[q];
        xout[(((n * 8 + o) * 40 + hy) * 40 + wx) * T + t] = a * 20.0f;
    }
}

// ---------------- sum-pool 2x2 (*pw) on DELAYED spikes, fused scan ----------
template<int C, int HO, int WO>
__global__ __launch_bounds__(256) void pool_spike(
    const uint8_t* __restrict__ in, const float* __restrict__ pw_ptr,
    uint8_t* __restrict__ out)
{
    int id = blockIdx.x * 256 + threadIdx.x;          // N*C*HO*WO
    int wx = id % WO;
    int hy = (id / WO) % HO;
    int c  = (id / (WO * HO)) % C;
    int n  = id / (WO * HO * C);
    float pw = pw_ptr[0];

    const uint8_t* p00 = in + (((n * C + c) * (2 * HO) + 2 * hy) * (2 * WO) + 2 * wx) * T;
    const uint8_t* p01 = p00 + T;
    const uint8_t* p10 = p00 + 2 * WO * T;
    const uint8_t* p11 = p10 + T;
    uint8_t* op = out + (((n * C + c) * HO + hy) * WO + wx) * T;

    float u = 0.f, v = 0.f;
    int prev = 0;  // pooled sum at t-1 (delay_shift)
    for (int tb = 0; tb < T / 4; tb++) {
        uchar4 a = *(const uchar4*)(p00 + tb * 4);
        uchar4 b = *(const uchar4*)(p01 + tb * 4);
        uchar4 cc = *(const uchar4*)(p10 + tb * 4);
        uchar4 d = *(const uchar4*)(p11 + tb * 4);
        int s1i = a.x + b.x + cc.x + d.x;
        int s2i = a.y + b.y + cc.y + d.y;
        int s3i = a.z + b.z + cc.z + d.z;
        float s0, s1, s2, s3;
        neuron_step(pw * (float)prev, u, v, s0);
        neuron_step(pw * (float)s1i,  u, v, s1);
        neuron_step(pw * (float)s2i,  u, v, s2);
        neuron_step(pw * (float)s3i,  u, v, s3);
        prev = a.w + b.w + cc.w + d.w;
        *(uchar4*)(op + tb * 4) =
            make_uchar4((unsigned char)s0, (unsigned char)s1,
                        (unsigned char)s2, (unsigned char)s3);
    }
}

// ---------------- conv phase A (grouped): COUT_PER outputs per thread -------
template<int CIN, int COUT_PER, int G, int H, int W>
__global__ __launch_bounds__(256) void conv_x_all(
    const uint8_t* __restrict__ in, const float* __restrict__ cw, float scale,
    float* __restrict__ xout)
{
    constexpr int BPG = H * W * T / 256;        // blocks per (n,g)
    int bid = blockIdx.x;
    int tIdx = (bid % BPG) * 256 + threadIdx.x;
    int gn = bid / BPG;
    int g = gn % G;                             // uniform
    int n = gn / G;                             // uniform
    int t  = tIdx % T;
    int wx = (tIdx / T) % W;
    int hy = tIdx / (T * W);

    int tm = (t == 0) ? 0 : (t - 1);            // delay_shift
    float tmask = (t == 0) ? 0.0f : 1.0f;

    bool okh[3] = {hy > 0, true, hy < H - 1};
    bool okw[3] = {wx > 0, true, wx < W - 1};

    const uint8_t* base = in + ((n * CIN * H + hy) * W + wx) * T + tm;
    const float* wbase = cw + g * COUT_PER * CIN * 9;   // uniform

    float acc[COUT_PER];
    #pragma unroll
    for (int oi = 0; oi < COUT_PER; oi++) acc[oi] = 0.f;

    #pragma unroll 1
    for (int c = 0; c < CIN; c++) {
        float tap[9];
        #pragma unroll
        for (int dh = 0; dh < 3; dh++)
            #pragma unroll
            for (int dw = 0; dw < 3; dw++) {
                bool ok = okh[dh] && okw[dw];
                tap[dh * 3 + dw] = ok ?
                    (float)base[(c * H * W + (dh - 1) * W + (dw - 1)) * T] : 0.f;
            }
        #pragma unroll
        for (int oi = 0; oi < COUT_PER; oi++) {
            if ((oi & 3) == 0) __builtin_amdgcn_sched_barrier(0);
            const float* wp = wbase + (oi * CIN + c) * 9;   // uniform
            float a = acc[oi];
            #pragma unroll
            for (int q = 0; q < 9; q++) a += wp[q] * tap[q];
            acc[oi] = a;
        }
    }

    float sm = scale * tmask;
    #pragma unroll
    for (int oi = 0; oi < COUT_PER; oi++) {
        int o = g * COUT_PER + oi;
        xout[((n * (G * COUT_PER) + o) * H * W + hy * W + wx) * T + t] = acc[oi] * sm;
    }
}

// ---------------- conv phase B: neuron scan over precomputed x --------------
__global__ __launch_bounds__(256) void scan_spike(
    const float* __restrict__ x, uint8_t* __restrict__ out, int rows)
{
    int id = blockIdx.x * 256 + threadIdx.x;
    if (id >= rows) return;
    const float4* xp = (const float4*)(x + (size_t)id * T);
    uchar4* op = (uchar4*)(out + (size_t)id * T);
    float u = 0.f, v = 0.f;
    for (int tb = 0; tb < T / 4; tb++) {
        float4 xv = xp[tb];
        float s0, s1, s2, s3;
        neuron_step(xv.x, u, v, s0); neuron_step(xv.y, u, v, s1);
        neuron_step(xv.z, u, v, s2); neuron_step(xv.w, u, v, s3);
        op[tb] = make_uchar4((unsigned char)s0, (unsigned char)s1,
                             (unsigned char)s2, (unsigned char)s3);
    }
}

// ---------------- W transpose: fwT[c][o] = fw[o][c] -------------------------
__global__ __launch_bounds__(256) void transpose_w(
    const float* __restrict__ fw, float* __restrict__ fwT)
{
    __shared__ float tile[32][33];
    int bc = blockIdx.x % 100;   // c-tile (3200/32)
    int bo = blockIdx.x / 100;   // o-tile (512/32)
    int lx = threadIdx.x & 31;
    int ly = threadIdx.x >> 5;   // 0..7
    #pragma unroll
    for (int k = 0; k < 4; k++)
        tile[ly + 8 * k][lx] = fw[(bo * 32 + ly + 8 * k) * 3200 + bc * 32 + lx];
    __syncthreads();
    #pragma unroll
    for (int k = 0; k < 4; k++)
        fwT[(bc * 32 + ly + 8 * k) * 512 + bo * 32 + lx] = tile[lx][ly + 8 * k];
}

// ---------------- FC GEMM: ypart[ks][n][t][o] = sum_c W[o][c]*s5[n][c][t-1] -
// o-tile 128 x t-tile 128 per block, 8x8/thread, c-split 8, c-chunk 56.
// Register double-buffer: preload next chunk (float4 W, u32 S-bytes) during
// compute; shfl_up provides the t-1 byte across lane boundary.
#define FC_CC 56
#define FC_ROW 140
#define FC_CRANGE 400

__global__ __launch_bounds__(256) void fc_gemm(
    const uint8_t* __restrict__ s5,   // [16][3200][128]
    const float* __restrict__ fwT,    // [3200][512] (transposed)
    float* __restrict__ ypart)        // [8][16][128][512]
{
    __shared__ float ldsW[FC_CC * FC_ROW];
    __shared__ float ldsS[FC_CC * FC_ROW];

    int bid = blockIdx.x;
    int ks = bid & 7;
    int n  = (bid >> 3) & 15;
    int ob = bid >> 7;                // 0..3
    int o0 = ob * 128;
    int cbase = ks * FC_CRANGE;
    int cend  = cbase + FC_CRANGE;

    int tid = threadIdx.x;
    int og = tid & 15;                // o_local = og*8 + i
    int tg = tid >> 4;                // t = tg*8 + j
    int wo = og * 8 + ((og >> 2) << 2);   // swizzled group offset
    int so = tg * 8 + ((tg >> 2) << 2);

    int srow = tid >> 5;              // staging row sub-index 0..7
    int scol = tid & 31;              // staging col group 0..31
    int sw   = scol * 4 + ((scol >> 3) << 2);  // LDS col offset (pad swizzle)

    float acc[8][8];
    #pragma unroll
    for (int i = 0; i < 8; i++)
        #pragma unroll
        for (int j = 0; j < 8; j++) acc[i][j] = 0.f;

    float4 wr4[7];
    uint32_t sr4[7];

    // preload chunk 0
    {
        int c0 = cbase;
        #pragma unroll
        for (int p = 0; p < 7; p++) {
            int c = c0 + p * 8 + srow;
            bool ok = c < cend;
            wr4[p] = ok ? *(const float4*)(fwT + (size_t)c * 512 + o0 + scol * 4)
                        : make_float4(0.f, 0.f, 0.f, 0.f);
            sr4[p] = ok ? *(const uint32_t*)(s5 + ((size_t)n * 3200 + c) * T + scol * 4)
                        : 0u;
        }
    }

    for (int ch = 0; ch < 8; ch++) {
        __syncthreads();   // prior compute done reading LDS
        #pragma unroll
        for (int p = 0; p < 7; p++) {
            int cc = p * 8 + srow;
            *(float4*)&ldsW[cc * FC_ROW + sw] = wr4[p];
            uint32_t raw = sr4[p];
            uint32_t prv = (uint32_t)__shfl_up((int)raw, 1);
            float f0 = (scol == 0) ? 0.f : (float)((prv >> 24) & 0xffu);
            float f1 = (float)(raw & 0xffu);
            float f2 = (float)((raw >> 8) & 0xffu);
            float f3 = (float)((raw >> 16) & 0xffu);
            *(float4*)&ldsS[cc * FC_ROW + sw] = make_float4(f0, f1, f2, f3);
        }
        __syncthreads();
        if (ch < 7) {
            int c0 = cbase + (ch + 1) * FC_CC;
            #pragma unroll
            for (int p = 0; p < 7; p++) {
                int c = c0 + p * 8 + srow;
                bool ok = c < cend;
                wr4[p] = ok ? *(const float4*)(fwT + (size_t)c * 512 + o0 + scol * 4)
                            : make_float4(0.f, 0.f, 0.f, 0.f);
                sr4[p] = ok ? *(const uint32_t*)(s5 + ((size_t)n * 3200 + c) * T + scol * 4)
                            : 0u;
            }
        }
        #pragma unroll 4
        for (int cc = 0; cc < FC_CC; cc++) {
            const float* wr = &ldsW[cc * FC_ROW];
            const float* sr = &ldsS[cc * FC_ROW];
            float4 w0 = *(const float4*)(wr + wo);
            float4 w1 = *(const float4*)(wr + wo + 4);
            float4 sA = *(const float4*)(sr + so);
            float4 sB = *(const float4*)(sr + so + 4);
            float wv[8] = {w0.x, w0.y, w0.z, w0.w, w1.x, w1.y, w1.z, w1.w};
            float sv[8] = {sA.x, sA.y, sA.z, sA.w, sB.x, sB.y, sB.z, sB.w};
            #pragma unroll
            for (int i = 0; i < 8; i++)
                #pragma unroll
                for (int j = 0; j < 8; j++)
                    acc[i][j] += wv[i] * sv[j];
        }
    }

    float* yp = ypart + ((ks * 16 + n) * T) * 512;
    #pragma unroll
    for (int j = 0; j < 8; j++) {
        int t = tg * 8 + j;
        float4 v0 = make_float4(acc[0][j], acc[1][j], acc[2][j], acc[3][j]);
        float4 v1 = make_float4(acc[4][j], acc[5][j], acc[6][j], acc[7][j]);
        *(float4*)&yp[t * 512 + o0 + og * 8]     = v0;
        *(float4*)&yp[t * 512 + o0 + og * 8 + 4] = v1;
    }
}

// ---------------- FC partial reduce + neuron scan + output delay ------------
__global__ __launch_bounds__(256) void fc_reduce(
    const float* __restrict__ yp, float* __restrict__ ys)
{
    int id = blockIdx.x * 256 + threadIdx.x;          // 1,048,576
    float x = 0.f;
    #pragma unroll
    for (int k = 0; k < 8; k++) x += yp[k * 1048576 + id];
    ys[id] = x;
}

__global__ __launch_bounds__(64) void fc_scan(
    const float* __restrict__ ysum,   // [16][128][512]
    float* __restrict__ out)          // [16][512][128]
{
    int id = blockIdx.x * 64 + threadIdx.x;           // 8192 (128 blocks)
    int o = id & 511;
    int n = id >> 9;
    float u = 0.f, v = 0.f;
    float prev = 0.f;                 // final delay_shift
    for (int tb = 0; tb < T / 4; tb++) {
        float b0, b1, b2, b3;
        float x, s;
        x = ysum[(n * T + tb * 4 + 0) * 512 + o]; neuron_step(x, u, v, s); b0 = prev; prev = s;
        x = ysum[(n * T + tb * 4 + 1) * 512 + o]; neuron_step(x, u, v, s); b1 = prev; prev = s;
        x = ysum[(n * T + tb * 4 + 2) * 512 + o]; neuron_step(x, u, v, s); b2 = prev; prev = s;
        x = ysum[(n * T + tb * 4 + 3) * 512 + o]; neuron_step(x, u, v, s); b3 = prev; prev = s;
        *(float4*)&out[((size_t)(n * 512 + o)) * T + tb * 4] = make_float4(b0, b1, b2, b3);
    }
}

// ---------------- launch ----------------------------------------------------
extern "C" void kernel_launch(void* const* d_in, const int* in_sizes, int n_in,
                              void* d_out, int out_size, void* d_ws, size_t ws_size,
                              hipStream_t stream) {
    const float* spike = (const float*)d_in[0];   // [16][2][40][40][128]
    const float* c1w   = (const float*)d_in[1];   // [8][2][3][3]
    const float* c2w   = (const float*)d_in[2];   // [16][8][3][3]
    const float* c3w   = (const float*)d_in[3];   // [32][16][3][3]
    const float* p1w   = (const float*)d_in[4];   // scalar
    const float* p2w   = (const float*)d_in[5];   // scalar
    const float* fcw   = (const float*)d_in[6];   // [512][3200]
    float* out = (float*)d_out;                   // [16][512][128]

    char* ws = (char*)d_ws;
    // ws layout (bytes):
    uint8_t* s1 = (uint8_t*)(ws);                 // 26,214,400
    uint8_t* s2 = (uint8_t*)(ws + 26214400);      //  6,553,600
    uint8_t* s3 = (uint8_t*)(ws + 32768000);      // 13,107,200
    uint8_t* s4 = (uint8_t*)(ws + 45875200);      //  3,276,800
    uint8_t* s5 = (uint8_t*)(ws + 49152000);      //  6,553,600
    float* xbuf  = (float*)(ws + 55705600);       // 52,428,800 (conv2/conv3 x)
    float* ypart = (float*)(ws + 55705600);       // 33,554,432 (aliases xbuf)
    float* ysumb = (float*)(ws + 55705600 + 33554432); // 4,194,304 (ends 93,454,336)
    float* xbuf1 = (float*)(ws + 93454336);       // 104,857,600 (conv1 x)
    float* fwT   = (float*)(ws + 93454336);       // 6,553,600 (reuses xbuf1 AFTER scan1)
    // total: 198,311,936 bytes

    conv1_x<<<12800, 256, 0, stream>>>(spike, c1w, xbuf1);
    scan_spike<<<800, 256, 0, stream>>>(xbuf1, s1, 204800);
    transpose_w<<<1600, 256, 0, stream>>>(fcw, fwT);   // xbuf1 dead from here
    pool_spike<8, 20, 20><<<200, 256, 0, stream>>>(s1, p1w, s2);
    conv_x_all<8, 16, 1, 20, 20><<<3200, 256, 0, stream>>>(s2, c2w, 100.0f, xbuf);
    scan_spike<<<400, 256, 0, stream>>>(xbuf, s3, 102400);
    pool_spike<16, 10, 10><<<100, 256, 0, stream>>>(s3, p2w, s4);
    conv_x_all<16, 16, 2, 10, 10><<<1600, 256, 0, stream>>>(s4, c3w, 100.0f, xbuf);
    scan_spike<<<200, 256, 0, stream>>>(xbuf, s5, 51200);
    fc_gemm<<<512, 256, 0, stream>>>(s5, fwT, ypart);
    fc_reduce<<<4096, 256, 0, stream>>>(ypart, ysumb);
    fc_scan<<<128, 64, 0, stream>>>(ysumb, out);
}

// Round 6
// 404.528 us; speedup vs baseline: 8.3520x; 1.4010x over previous
//
#include <hip/hip_runtime.h>
#include <stdint.h>

// SNN forward: conv1+spike -> pool1+spike -> conv2+spike -> pool2+spike ->
// conv3+spike -> fc+spike, each with delay_shift between layers.
// Neuron: u = 0.75u + x; v = 0.96875v + u; s = (v>=100); v *= (1-s).
// Intermediate spikes as uint8 in d_ws.

#define T 128
#define AI 0.75f
#define AV 0.96875f
#define THETA 100.0f

__device__ __forceinline__ void neuron_step(float x, float& u, float& v, float& s) {
    u = AI * u + x;
    v = AV * v + u;
    s = (v >= THETA) ? 1.0f : 0.0f;
    v = v * (1.0f - s);
}

// ---------------- conv1 phase A: x[n][o][h][w][t], lanes over t -------------
__global__ __launch_bounds__(256) void conv1_x(
    const float* __restrict__ in, const float* __restrict__ cw,
    float* __restrict__ xout)
{
    int bid = blockIdx.x;                       // 12800
    int tIdx = (bid % 800) * 256 + threadIdx.x; // within [40][40][128]
    int n = bid / 800;
    int t  = tIdx % T;
    int wx = (tIdx / T) % 40;
    int hy = tIdx / (T * 40);

    float val[18];
    #pragma unroll
    for (int c = 0; c < 2; c++)
      #pragma unroll
      for (int dh = -1; dh <= 1; dh++)
        #pragma unroll
        for (int dw = -1; dw <= 1; dw++) {
            int q = c * 9 + (dh + 1) * 3 + (dw + 1);
            int hh = hy + dh, ww = wx + dw;
            bool ok = (hh >= 0) && (hh < 40) && (ww >= 0) && (ww < 40);
            val[q] = ok ? in[(((n * 2 + c) * 40 + hh) * 40 + ww) * T + t] : 0.0f;
        }

    #pragma unroll 1
    for (int o = 0; o < 8; o++) {
        const float* wp = cw + o * 18;          // uniform -> s_load
        float a = 0.f;
        #pragma unroll
        for (int q = 0; q < 18; q++) a += wp[q] * val[q];
        xout[(((n * 8 + o) * 40 + hy) * 40 + wx) * T + t] = a * 20.0f;
    }
}

// ---------------- scan (transposed via LDS): fp32 x rows -> u8 spikes -------
// Block = 256 rows. Per 16-t chunk: coalesced float4 loads -> LDS tile
// (row stride 20 floats: scan reads free 2-way), per-thread scan from LDS,
// spikes packed in registers; final 128B/row store via 8x dwordx4 (L2 merges).
__global__ __launch_bounds__(256) void scan_spike_t(
    const float* __restrict__ x, uint8_t* __restrict__ out)
{
    __shared__ float lds[256 * 20];
    int tid = threadIdx.x;
    size_t r0 = (size_t)blockIdx.x * 256;
    const float* xb = x + r0 * T;

    float u = 0.f, v = 0.f;
    uint32_t ob[32];

    for (int tb = 0; tb < 8; tb++) {
        __syncthreads();
        #pragma unroll
        for (int k = 0; k < 4; k++) {
            int f = tid + k * 256;              // 0..1023
            int row = f >> 2, q = f & 3;
            float4 vv = *(const float4*)(xb + (size_t)row * T + tb * 16 + q * 4);
            *(float4*)&lds[row * 20 + q * 4] = vv;
        }
        __syncthreads();
        #pragma unroll
        for (int k = 0; k < 4; k++) {
            float4 xv = *(const float4*)&lds[tid * 20 + k * 4];
            float s0, s1, s2, s3;
            neuron_step(xv.x, u, v, s0); neuron_step(xv.y, u, v, s1);
            neuron_step(xv.z, u, v, s2); neuron_step(xv.w, u, v, s3);
            ob[tb * 4 + k] = (uint32_t)s0 | ((uint32_t)s1 << 8) |
                             ((uint32_t)s2 << 16) | ((uint32_t)s3 << 24);
        }
    }

    uint32_t* op = (uint32_t*)(out + (r0 + tid) * T);
    #pragma unroll
    for (int k = 0; k < 8; k++)
        *(uint4*)&op[k * 4] = make_uint4(ob[k*4], ob[k*4+1], ob[k*4+2], ob[k*4+3]);
}

// ---------------- pool phase A: 2x2 spatial sum (u8, parallel over t) -------
template<int C, int HO, int WO>
__global__ __launch_bounds__(256) void pool_sum(
    const uint8_t* __restrict__ in, uint8_t* __restrict__ out)
{
    int id = blockIdx.x * 256 + threadIdx.x;    // rows*32
    int tq = id & 31;
    int orow = id >> 5;
    int wx = orow % WO;
    int hy = (orow / WO) % HO;
    int c  = (orow / (WO * HO)) % C;
    int n  = orow / (WO * HO * C);

    const uint8_t* p00 = in + (((n * C + c) * (2 * HO) + 2 * hy) * (2 * WO) + 2 * wx) * T;
    uchar4 a = *(const uchar4*)(p00 + tq * 4);
    uchar4 b = *(const uchar4*)(p00 + T + tq * 4);
    uchar4 cc = *(const uchar4*)(p00 + 2 * WO * T + tq * 4);
    uchar4 d = *(const uchar4*)(p00 + 2 * WO * T + T + tq * 4);
    *(uchar4*)(out + (size_t)orow * T + tq * 4) =
        make_uchar4(a.x + b.x + cc.x + d.x, a.y + b.y + cc.y + d.y,
                    a.z + b.z + cc.z + d.z, a.w + b.w + cc.w + d.w);
}

// ---------------- pool phase B: transposed scan on u8 sums (pw, delay) ------
// x_t = pw * pooledsum[t-1]; byte-carry register implements the delay.
__global__ __launch_bounds__(256) void pool_scan(
    const uint8_t* __restrict__ ps, const float* __restrict__ pw_ptr,
    uint8_t* __restrict__ out)
{
    __shared__ uint32_t lds[256 * 20];
    int tid = threadIdx.x;
    size_t r0 = (size_t)blockIdx.x * 256;
    const uint32_t* pb = (const uint32_t*)(ps + r0 * T);
    float pw = pw_ptr[0];

    float u = 0.f, v = 0.f;
    uint32_t ob[32];
    uint32_t carry = 0;                          // pooled sum byte at t-1

    for (int tb = 0; tb < 2; tb++) {             // 2 chunks of 64 t (16 u32/row)
        __syncthreads();
        #pragma unroll
        for (int k = 0; k < 4; k++) {
            int f = tid + k * 256;               // 0..1023
            int row = f >> 2, q = f & 3;
            uint4 vv = *(const uint4*)(pb + (size_t)row * 32 + tb * 16 + q * 4);
            *(uint4*)&lds[row * 20 + q * 4] = vv;
        }
        __syncthreads();
        #pragma unroll
        for (int q = 0; q < 4; q++) {
            uint4 w = *(const uint4*)&lds[tid * 20 + q * 4];
            uint32_t words[4] = {w.x, w.y, w.z, w.w};
            #pragma unroll
            for (int j = 0; j < 4; j++) {
                uint32_t cur = words[j];
                uint32_t del = (cur << 8) | carry;   // delayed bytes
                carry = cur >> 24;
                float s0, s1, s2, s3;
                neuron_step(pw * (float)(del & 0xffu),         u, v, s0);
                neuron_step(pw * (float)((del >> 8) & 0xffu),  u, v, s1);
                neuron_step(pw * (float)((del >> 16) & 0xffu), u, v, s2);
                neuron_step(pw * (float)((del >> 24) & 0xffu), u, v, s3);
                ob[tb * 16 + q * 4 + j] = (uint32_t)s0 | ((uint32_t)s1 << 8) |
                                          ((uint32_t)s2 << 16) | ((uint32_t)s3 << 24);
            }
        }
    }

    uint32_t* op = (uint32_t*)(out + (r0 + tid) * T);
    #pragma unroll
    for (int k = 0; k < 8; k++)
        *(uint4*)&op[k * 4] = make_uint4(ob[k*4], ob[k*4+1], ob[k*4+2], ob[k*4+3]);
}

// ---------------- conv phase A (grouped): COUT_PER outputs per thread -------
template<int CIN, int COUT_PER, int G, int H, int W>
__global__ __launch_bounds__(256) void conv_x_all(
    const uint8_t* __restrict__ in, const float* __restrict__ cw, float scale,
    float* __restrict__ xout)
{
    constexpr int BPG = H * W * T / 256;        // blocks per (n,g)
    int bid = blockIdx.x;
    int tIdx = (bid % BPG) * 256 + threadIdx.x;
    int gn = bid / BPG;
    int g = gn % G;                             // uniform
    int n = gn / G;                             // uniform
    int t  = tIdx % T;
    int wx = (tIdx / T) % W;
    int hy = tIdx / (T * W);

    int tm = (t == 0) ? 0 : (t - 1);            // delay_shift
    float tmask = (t == 0) ? 0.0f : 1.0f;

    bool okh[3] = {hy > 0, true, hy < H - 1};
    bool okw[3] = {wx > 0, true, wx < W - 1};

    const uint8_t* base = in + ((n * CIN * H + hy) * W + wx) * T + tm;
    const float* wbase = cw + g * COUT_PER * CIN * 9;   // uniform

    float acc[COUT_PER];
    #pragma unroll
    for (int oi = 0; oi < COUT_PER; oi++) acc[oi] = 0.f;

    #pragma unroll 1
    for (int c = 0; c < CIN; c++) {
        float tap[9];
        #pragma unroll
        for (int dh = 0; dh < 3; dh++)
            #pragma unroll
            for (int dw = 0; dw < 3; dw++) {
                bool ok = okh[dh] && okw[dw];
                tap[dh * 3 + dw] = ok ?
                    (float)base[(c * H * W + (dh - 1) * W + (dw - 1)) * T] : 0.f;
            }
        #pragma unroll
        for (int oi = 0; oi < COUT_PER; oi++) {
            if ((oi & 3) == 0) __builtin_amdgcn_sched_barrier(0);
            const float* wp = wbase + (oi * CIN + c) * 9;   // uniform
            float a = acc[oi];
            #pragma unroll
            for (int q = 0; q < 9; q++) a += wp[q] * tap[q];
            acc[oi] = a;
        }
    }

    float sm = scale * tmask;
    #pragma unroll
    for (int oi = 0; oi < COUT_PER; oi++) {
        int o = g * COUT_PER + oi;
        xout[((n * (G * COUT_PER) + o) * H * W + hy * W + wx) * T + t] = acc[oi] * sm;
    }
}

// ---------------- W transpose: fwT[c][o] = fw[o][c] -------------------------
__global__ __launch_bounds__(256) void transpose_w(
    const float* __restrict__ fw, float* __restrict__ fwT)
{
    __shared__ float tile[32][33];
    int bc = blockIdx.x % 100;   // c-tile (3200/32)
    int bo = blockIdx.x / 100;   // o-tile (512/32)
    int lx = threadIdx.x & 31;
    int ly = threadIdx.x >> 5;   // 0..7
    #pragma unroll
    for (int k = 0; k < 4; k++)
        tile[ly + 8 * k][lx] = fw[(bo * 32 + ly + 8 * k) * 3200 + bc * 32 + lx];
    __syncthreads();
    #pragma unroll
    for (int k = 0; k < 4; k++)
        fwT[(bc * 32 + ly + 8 * k) * 512 + bo * 32 + lx] = tile[lx][ly + 8 * k];
}

// ---------------- FC GEMM: ypart[ks][n][t][o] = sum_c W[o][c]*s5[n][c][t-1] -
#define FC_CC 56
#define FC_ROW 140
#define FC_CRANGE 400

__global__ __launch_bounds__(256) void fc_gemm(
    const uint8_t* __restrict__ s5,   // [16][3200][128]
    const float* __restrict__ fwT,    // [3200][512] (transposed)
    float* __restrict__ ypart)        // [8][16][128][512]
{
    __shared__ float ldsW[FC_CC * FC_ROW];
    __shared__ float ldsS[FC_CC * FC_ROW];

    int bid = blockIdx.x;
    int ks = bid & 7;
    int n  = (bid >> 3) & 15;
    int ob = bid >> 7;                // 0..3
    int o0 = ob * 128;
    int cbase = ks * FC_CRANGE;
    int cend  = cbase + FC_CRANGE;

    int tid = threadIdx.x;
    int og = tid & 15;
    int tg = tid >> 4;
    int wo = og * 8 + ((og >> 2) << 2);
    int so = tg * 8 + ((tg >> 2) << 2);

    int srow = tid >> 5;              // 0..7
    int scol = tid & 31;              // 0..31
    int sw   = scol * 4 + ((scol >> 3) << 2);

    float acc[8][8];
    #pragma unroll
    for (int i = 0; i < 8; i++)
        #pragma unroll
        for (int j = 0; j < 8; j++) acc[i][j] = 0.f;

    float4 wr4[7];
    uint32_t sr4[7];

    {
        int c0 = cbase;
        #pragma unroll
        for (int p = 0; p < 7; p++) {
            int c = c0 + p * 8 + srow;
            bool ok = c < cend;
            wr4[p] = ok ? *(const float4*)(fwT + (size_t)c * 512 + o0 + scol * 4)
                        : make_float4(0.f, 0.f, 0.f, 0.f);
            sr4[p] = ok ? *(const uint32_t*)(s5 + ((size_t)n * 3200 + c) * T + scol * 4)
                        : 0u;
        }
    }

    for (int ch = 0; ch < 8; ch++) {
        __syncthreads();
        #pragma unroll
        for (int p = 0; p < 7; p++) {
            int cc = p * 8 + srow;
            *(float4*)&ldsW[cc * FC_ROW + sw] = wr4[p];
            uint32_t raw = sr4[p];
            uint32_t prv = (uint32_t)__shfl_up((int)raw, 1);
            float f0 = (scol == 0) ? 0.f : (float)((prv >> 24) & 0xffu);
            float f1 = (float)(raw & 0xffu);
            float f2 = (float)((raw >> 8) & 0xffu);
            float f3 = (float)((raw >> 16) & 0xffu);
            *(float4*)&ldsS[cc * FC_ROW + sw] = make_float4(f0, f1, f2, f3);
        }
        __syncthreads();
        if (ch < 7) {
            int c0 = cbase + (ch + 1) * FC_CC;
            #pragma unroll
            for (int p = 0; p < 7; p++) {
                int c = c0 + p * 8 + srow;
                bool ok = c < cend;
                wr4[p] = ok ? *(const float4*)(fwT + (size_t)c * 512 + o0 + scol * 4)
                            : make_float4(0.f, 0.f, 0.f, 0.f);
                sr4[p] = ok ? *(const uint32_t*)(s5 + ((size_t)n * 3200 + c) * T + scol * 4)
                            : 0u;
            }
        }
        #pragma unroll 4
        for (int cc = 0; cc < FC_CC; cc++) {
            const float* wr = &ldsW[cc * FC_ROW];
            const float* sr = &ldsS[cc * FC_ROW];
            float4 w0 = *(const float4*)(wr + wo);
            float4 w1 = *(const float4*)(wr + wo + 4);
            float4 sA = *(const float4*)(sr + so);
            float4 sB = *(const float4*)(sr + so + 4);
            float wv[8] = {w0.x, w0.y, w0.z, w0.w, w1.x, w1.y, w1.z, w1.w};
            float sv[8] = {sA.x, sA.y, sA.z, sA.w, sB.x, sB.y, sB.z, sB.w};
            #pragma unroll
            for (int i = 0; i < 8; i++)
                #pragma unroll
                for (int j = 0; j < 8; j++)
                    acc[i][j] += wv[i] * sv[j];
        }
    }

    float* yp = ypart + ((ks * 16 + n) * T) * 512;
    #pragma unroll
    for (int j = 0; j < 8; j++) {
        int t = tg * 8 + j;
        float4 v0 = make_float4(acc[0][j], acc[1][j], acc[2][j], acc[3][j]);
        float4 v1 = make_float4(acc[4][j], acc[5][j], acc[6][j], acc[7][j]);
        *(float4*)&yp[t * 512 + o0 + og * 8]     = v0;
        *(float4*)&yp[t * 512 + o0 + og * 8 + 4] = v1;
    }
}

// ---------------- FC partial reduce + neuron scan + output delay ------------
__global__ __launch_bounds__(256) void fc_reduce(
    const float* __restrict__ yp, float* __restrict__ ys)
{
    int id = blockIdx.x * 256 + threadIdx.x;          // 1,048,576
    float x = 0.f;
    #pragma unroll
    for (int k = 0; k < 8; k++) x += yp[k * 1048576 + id];
    ys[id] = x;
}

__global__ __launch_bounds__(64) void fc_scan(
    const float* __restrict__ ysum,   // [16][128][512]
    float* __restrict__ out)          // [16][512][128]
{
    int id = blockIdx.x * 64 + threadIdx.x;           // 8192 (128 blocks)
    int o = id & 511;
    int n = id >> 9;
    float u = 0.f, v = 0.f;
    float prev = 0.f;                 // final delay_shift
    for (int tb = 0; tb < T / 4; tb++) {
        float b0, b1, b2, b3;
        float x, s;
        x = ysum[(n * T + tb * 4 + 0) * 512 + o]; neuron_step(x, u, v, s); b0 = prev; prev = s;
        x = ysum[(n * T + tb * 4 + 1) * 512 + o]; neuron_step(x, u, v, s); b1 = prev; prev = s;
        x = ysum[(n * T + tb * 4 + 2) * 512 + o]; neuron_step(x, u, v, s); b2 = prev; prev = s;
        x = ysum[(n * T + tb * 4 + 3) * 512 + o]; neuron_step(x, u, v, s); b3 = prev; prev = s;
        *(float4*)&out[((size_t)(n * 512 + o)) * T + tb * 4] = make_float4(b0, b1, b2, b3);
    }
}

// ---------------- launch ----------------------------------------------------
extern "C" void kernel_launch(void* const* d_in, const int* in_sizes, int n_in,
                              void* d_out, int out_size, void* d_ws, size_t ws_size,
                              hipStream_t stream) {
    const float* spike = (const float*)d_in[0];   // [16][2][40][40][128]
    const float* c1w   = (const float*)d_in[1];   // [8][2][3][3]
    const float* c2w   = (const float*)d_in[2];   // [16][8][3][3]
    const float* c3w   = (const float*)d_in[3];   // [32][16][3][3]
    const float* p1w   = (const float*)d_in[4];   // scalar
    const float* p2w   = (const float*)d_in[5];   // scalar
    const float* fcw   = (const float*)d_in[6];   // [512][3200]
    float* out = (float*)d_out;                   // [16][512][128]

    char* ws = (char*)d_ws;
    // ws layout (bytes):
    uint8_t* s1 = (uint8_t*)(ws);                 // 26,214,400
    uint8_t* s2 = (uint8_t*)(ws + 26214400);      //  6,553,600
    uint8_t* s3 = (uint8_t*)(ws + 32768000);      // 13,107,200
    uint8_t* s4 = (uint8_t*)(ws + 45875200);      //  3,276,800
    uint8_t* s5 = (uint8_t*)(ws + 49152000);      //  6,553,600
    float* xbuf  = (float*)(ws + 55705600);       // 52,428,800 (conv2/conv3 x)
    uint8_t* psum = (uint8_t*)(ws + 55705600);    // pool sums (alias xbuf; dead then)
    float* ypart = (float*)(ws + 55705600);       // 33,554,432 (aliases xbuf)
    float* ysumb = (float*)(ws + 55705600 + 33554432); // 4,194,304 (ends 93,454,336)
    float* xbuf1 = (float*)(ws + 93454336);       // 104,857,600 (conv1 x)
    float* fwT   = (float*)(ws + 93454336);       // 6,553,600 (reuses xbuf1 AFTER scan1)
    // total: 198,311,936 bytes

    conv1_x<<<12800, 256, 0, stream>>>(spike, c1w, xbuf1);
    scan_spike_t<<<800, 256, 0, stream>>>(xbuf1, s1);
    transpose_w<<<1600, 256, 0, stream>>>(fcw, fwT);   // xbuf1 dead from here

    pool_sum<8, 20, 20><<<6400, 256, 0, stream>>>(s1, psum);
    pool_scan<<<200, 256, 0, stream>>>(psum, p1w, s2);

    conv_x_all<8, 16, 1, 20, 20><<<3200, 256, 0, stream>>>(s2, c2w, 100.0f, xbuf);
    scan_spike_t<<<400, 256, 0, stream>>>(xbuf, s3);

    pool_sum<16, 10, 10><<<3200, 256, 0, stream>>>(s3, psum);
    pool_scan<<<100, 256, 0, stream>>>(psum, p2w, s4);

    conv_x_all<16, 16, 2, 10, 10><<<1600, 256, 0, stream>>>(s4, c3w, 100.0f, xbuf);
    scan_spike_t<<<200, 256, 0, stream>>>(xbuf, s5);

    fc_gemm<<<512, 256, 0, stream>>>(s5, fwT, ypart);
    fc_reduce<<<4096, 256, 0, stream>>>(ypart, ysumb);
    fc_scan<<<128, 64, 0, stream>>>(ysumb, out);
}